// Round 6
// baseline (570.337 us; speedup 1.0000x reference)
//
#include <hip/hip_runtime.h>
#include <math.h>

#define N_NODES 50000
#define N_EDGES 800000
#define D 128
#define E_DIM 16
#define DEPTH 3

typedef _Float16 half2_t __attribute__((ext_vector_type(2)));
typedef _Float16 half4_t __attribute__((ext_vector_type(4)));
typedef _Float16 half8_t __attribute__((ext_vector_type(8)));
typedef float floatx4 __attribute__((ext_vector_type(4)));

#if defined(__has_builtin)
#if __has_builtin(__builtin_amdgcn_fdot2)
#define FDOT2(a, b, c) __builtin_amdgcn_fdot2((a), (b), (c), false)
#endif
#endif
#ifndef FDOT2
static __device__ __forceinline__ float fdot2_sw(half2_t a, half2_t b, float c) {
    return fmaf((float)a.x, (float)b.x, fmaf((float)a.y, (float)b.y, c));
}
#define FDOT2(a, b, c) fdot2_sw((a), (b), (c))
#endif

static __device__ __forceinline__ half2_t bch2(unsigned u) {
    return __builtin_bit_cast(half2_t, u);
}

// ---------------- CSR build (by dst) ----------------

__global__ void k_hist(const int* __restrict__ dst, int* __restrict__ deg) {
    int e = blockIdx.x * blockDim.x + threadIdx.x;
    if (e < N_EDGES) atomicAdd(&deg[dst[e]], 1);
}

__global__ void k_scan1(const int* __restrict__ deg, int* __restrict__ out1,
                        int* __restrict__ bsum) {
    __shared__ int s[256];
    int t = threadIdx.x;
    int base = blockIdx.x * 1024;
    int v[4]; int sum = 0;
#pragma unroll
    for (int j = 0; j < 4; j++) {
        int idx = base + t * 4 + j;
        int x = (idx < N_NODES) ? deg[idx] : 0;
        v[j] = x; sum += x;
    }
    s[t] = sum;
    __syncthreads();
    for (int d2 = 1; d2 < 256; d2 <<= 1) {
        int val = (t >= d2) ? s[t - d2] : 0;
        __syncthreads();
        s[t] += val;
        __syncthreads();
    }
    int run = (t > 0) ? s[t - 1] : 0;
#pragma unroll
    for (int j = 0; j < 4; j++) {
        int idx = base + t * 4 + j;
        run += v[j];
        if (idx < N_NODES) out1[idx] = run;
    }
    if (t == 255) bsum[blockIdx.x] = s[255];
}

__global__ void k_scanadd(int* __restrict__ off, const int* __restrict__ bsum1,
                          int* __restrict__ head) {
    int i = blockIdx.x * blockDim.x + threadIdx.x;
    if (i == 0) { off[0] = 0; head[0] = 0; }
    if (i < N_NODES) {
        int nb = i >> 10;
        int add = 0;
        for (int j = 0; j < nb; j++) add += bsum1[j];
        int v = off[i + 1] + add;
        off[i + 1] = v;
        if (i + 1 < N_NODES) head[i + 1] = v;
    }
}

// scatter: place src index AND f16-converted edge_attr row at sorted position
__global__ void k_scatter(const int* __restrict__ src, const int* __restrict__ dst,
                          const float* __restrict__ ea, int* __restrict__ head,
                          int* __restrict__ srcs, _Float16* __restrict__ ea_s) {
    int e = blockIdx.x * blockDim.x + threadIdx.x;
    if (e < N_EDGES) {
        int d = dst[e];
        int pos = atomicAdd(&head[d], 1);
        srcs[pos] = src[e];
        const float4* ep = (const float4*)(ea + (size_t)e * E_DIM);
        float4 a = ep[0], b = ep[1], c = ep[2], f = ep[3];
        half8_t h0 = {(_Float16)a.x, (_Float16)a.y, (_Float16)a.z, (_Float16)a.w,
                      (_Float16)b.x, (_Float16)b.y, (_Float16)b.z, (_Float16)b.w};
        half8_t h1 = {(_Float16)c.x, (_Float16)c.y, (_Float16)c.z, (_Float16)c.w,
                      (_Float16)f.x, (_Float16)f.y, (_Float16)f.z, (_Float16)f.w};
        _Float16* op = ea_s + (size_t)pos * E_DIM;
        *(half8_t*)op = h0;
        *(half8_t*)(op + 8) = h1;
    }
}

// ---------------- prep: x f16 convert + MFMA weight packing ----------------

#define NB_X 3125    // N_NODES*D/8/256
#define NB_W 384     // 6*16384/256

__global__ void k_prep(const float* __restrict__ x,
                       const float* __restrict__ W1, const float* __restrict__ W2,
                       _Float16* __restrict__ xh, _Float16* __restrict__ Wp) {
    int b = blockIdx.x;
    if (b < NB_X) {
        int base = (b * 256 + threadIdx.x) * 8;
        float4 a = *(const float4*)(x + base);
        float4 c = *(const float4*)(x + base + 4);
        half8_t h = {(_Float16)a.x, (_Float16)a.y, (_Float16)a.z, (_Float16)a.w,
                     (_Float16)c.x, (_Float16)c.y, (_Float16)c.z, (_Float16)c.w};
        *(half8_t*)(xh + base) = h;
    } else {
        int t = (b - NB_X) * 256 + threadIdx.x;
        int j    = t & 7;
        int lane = (t >> 3) & 63;
        int nb   = (t >> 9) & 7;
        int kb   = (t >> 12) & 3;
        int mat  = t >> 14;
        int layer = mat >> 1, which = mat & 1;
        const float* Wsrc = (which ? W2 : W1) + (size_t)layer * D * D;
        int k = kb * 32 + (lane >> 4) * 8 + j;
        int n = nb * 16 + (lane & 15);
        Wp[t] = (_Float16)Wsrc[k * D + n];
    }
}

// ---------------- per-layer: aggregation ----------------
// One wave per dst node; 2 groups x 32 lanes; lane = 4 feats (4c..4c+3).
// Group g owns a CONTIGUOUS half of the node's sorted edge range (keeps the
// srcs / ea_s streams sequential -> L1 hits, induction-addressed ea).
// 4-slot rotating register pipeline with distance-4 held src values:
// up to 8 edges/wave in flight; only the x-gather is a dependent load.

__global__ __launch_bounds__(256) void k_agg(
    const _Float16* __restrict__ xb, const _Float16* __restrict__ ea_s,
    const int* __restrict__ srcs, const int* __restrict__ off,
    const float* __restrict__ We_l, const float* __restrict__ be_l,
    const float* __restrict__ eps_ptr, _Float16* __restrict__ h0) {
    int n = blockIdx.x * 4 + (threadIdx.x >> 6);
    int lane = threadIdx.x & 63;
    int g = lane >> 5;        // group 0/1
    int c = lane & 31;        // feats 4c..4c+3

    half2_t w2[8][4];
    float bev[4];
    {
        float4 bb = *(const float4*)(be_l + 4 * c);
        bev[0] = bb.x; bev[1] = bb.y; bev[2] = bb.z; bev[3] = bb.w;
#pragma unroll
        for (int kp = 0; kp < 8; kp++) {
            float4 r0 = *(const float4*)(We_l + (2 * kp) * D + 4 * c);
            float4 r1 = *(const float4*)(We_l + (2 * kp + 1) * D + 4 * c);
            w2[kp][0] = half2_t{(_Float16)r0.x, (_Float16)r1.x};
            w2[kp][1] = half2_t{(_Float16)r0.y, (_Float16)r1.y};
            w2[kp][2] = half2_t{(_Float16)r0.z, (_Float16)r1.z};
            w2[kp][3] = half2_t{(_Float16)r0.w, (_Float16)r1.w};
        }
    }

    float acc0 = 0.f, acc1 = 0.f, acc2 = 0.f, acc3 = 0.f;
    int t0 = __builtin_amdgcn_readfirstlane(off[n]);
    int t1 = __builtin_amdgcn_readfirstlane(off[n + 1]);
    int deg = t1 - t0;

    if (deg > 0) {
        int hf  = (deg + 1) >> 1;            // group-0 count == step count N
        int cnt = g ? (deg - hf) : hf;       // this group's edge count
        int cl  = cnt - 1;
        int base = t0 + (g ? hf : 0);

        // pipeline state (constant-indexed -> registers)
        int   sv[4];                         // held src value for next refill
        uint4 lo[4], hi[4];                  // ea row (8 half2 dwords)
        half2_t xva[4], xvb[4];              // x feats (2 half2)

        auto idxof = [&](int i) {
            int ii = min(i, cl); ii = max(ii, 0);
            return min(base + ii, N_EDGES - 1);
        };
        auto load_x = [&](int s, int srcrow) {
            uint2 xr = *(const uint2*)(xb + (size_t)srcrow * D + 4 * c);
            xva[s] = bch2(xr.x); xvb[s] = bch2(xr.y);
        };
        auto load_ea = [&](int s, int i) {
            const uint4* er = (const uint4*)(ea_s + (size_t)idxof(i) * E_DIM);
            lo[s] = er[0]; hi[s] = er[1];
        };
        auto comp = [&](int s, int i) {
            float p0 = bev[0], p1 = bev[1], p2 = bev[2], p3 = bev[3];
#define KSTEP(dw, kp)                                   \
            { half2_t e2 = bch2(dw);                    \
              p0 = FDOT2(e2, w2[kp][0], p0);            \
              p1 = FDOT2(e2, w2[kp][1], p1);            \
              p2 = FDOT2(e2, w2[kp][2], p2);            \
              p3 = FDOT2(e2, w2[kp][3], p3); }
            KSTEP(lo[s].x, 0) KSTEP(lo[s].y, 1) KSTEP(lo[s].z, 2) KSTEP(lo[s].w, 3)
            KSTEP(hi[s].x, 4) KSTEP(hi[s].y, 5) KSTEP(hi[s].z, 6) KSTEP(hi[s].w, 7)
#undef KSTEP
            float m0 = fmaxf((float)xva[s].x + p0, 0.f);
            float m1 = fmaxf((float)xva[s].y + p1, 0.f);
            float m2 = fmaxf((float)xvb[s].x + p2, 0.f);
            float m3 = fmaxf((float)xvb[s].y + p3, 0.f);
            float sel = (i < cnt) ? 1.f : 0.f;
            acc0 = fmaf(m0, sel, acc0);
            acc1 = fmaf(m1, sel, acc1);
            acc2 = fmaf(m2, sel, acc2);
            acc3 = fmaf(m3, sel, acc3);
        };

        // ---- prolog: fill slots with indices 0..3; hold srcs for 4..7 ----
        {
            int tmp0 = srcs[idxof(0)], tmp1 = srcs[idxof(1)];
            int tmp2 = srcs[idxof(2)], tmp3 = srcs[idxof(3)];
            load_ea(0, 0); load_ea(1, 1); load_ea(2, 2); load_ea(3, 3);
            load_x(0, tmp0); load_x(1, tmp1); load_x(2, tmp2); load_x(3, tmp3);
            sv[0] = srcs[idxof(4)]; sv[1] = srcs[idxof(5)];
            sv[2] = srcs[idxof(6)]; sv[3] = srcs[idxof(7)];
        }

        int i = 0;
        for (; i + 4 <= hf; i += 4) {
#define STEP(s)                                          \
            { comp(s, i + s);                            \
              load_x(s, sv[s]);                          \
              load_ea(s, i + s + 4);                     \
              sv[s] = srcs[idxof(i + s + 8)]; }
            STEP(0) STEP(1) STEP(2) STEP(3)
#undef STEP
        }
        if (i < hf) {
            comp(0, i + 0); comp(1, i + 1); comp(2, i + 2); comp(3, i + 3);
        }
    }

    // cross-group reduction: lane l += lane l^32
    acc0 += __shfl_xor(acc0, 32, 64);
    acc1 += __shfl_xor(acc1, 32, 64);
    acc2 += __shfl_xor(acc2, 32, 64);
    acc3 += __shfl_xor(acc3, 32, 64);

    if (g == 0) {
        float epsv = 1.0f + eps_ptr[0];
        uint2 xr = *(const uint2*)(xb + (size_t)n * D + 4 * c);
        half2_t xl = bch2(xr.x), xh = bch2(xr.y);
        half2_t o0 = half2_t{(_Float16)fmaf(epsv, (float)xl.x, acc0),
                             (_Float16)fmaf(epsv, (float)xl.y, acc1)};
        half2_t o1 = half2_t{(_Float16)fmaf(epsv, (float)xh.x, acc2),
                             (_Float16)fmaf(epsv, (float)xh.y, acc3)};
        uint2 ow;
        ow.x = __builtin_bit_cast(unsigned, o0);
        ow.y = __builtin_bit_cast(unsigned, o1);
        *(uint2*)(h0 + (size_t)n * D + 4 * c) = ow;
    }
}

// ---------------- per-layer: fused node MLP via MFMA f16 ----------------

__device__ __forceinline__ float gelu_fast(float v) {
    // tanh-form GELU via sigmoid (max abs err vs exact erf-GELU ~3e-3)
    float u = v * v;
    float t = v * fmaf(0.044715f, u, 1.0f);
    float s = 1.0f / (1.0f + __expf(-1.5957691216f * t));
    return v * s;
}

template <bool LAST>
__global__ __launch_bounds__(256) void k_mlp(
    const _Float16* __restrict__ h0, const _Float16* __restrict__ W1p,
    const float* __restrict__ b1, const _Float16* __restrict__ W2p,
    const float* __restrict__ b2, float* __restrict__ outf,
    _Float16* __restrict__ outh) {
    __shared__ _Float16 sH[64 * 136];
    __shared__ _Float16 sG[64 * 136];
    int n0 = blockIdx.x * 64;
    int t = threadIdx.x;

    for (int cc = t; cc < 1024; cc += 256) {
        int row = cc >> 4, c4 = cc & 15;
        uint4 v = make_uint4(0, 0, 0, 0);
        if (n0 + row < N_NODES)
            v = *(const uint4*)(h0 + (size_t)(n0 + row) * D + c4 * 8);
        *(uint4*)&sH[row * 136 + c4 * 8] = v;
    }
    __syncthreads();

    int w = t >> 6, lane = t & 63, q = lane >> 4, r16 = lane & 15;
    int mrow = w * 16 + r16;

    floatx4 acc[8];
#pragma unroll
    for (int nb = 0; nb < 8; nb++) acc[nb] = floatx4{0.f, 0.f, 0.f, 0.f};
#pragma unroll
    for (int kb = 0; kb < 4; kb++) {
        half8_t av = *(const half8_t*)&sH[mrow * 136 + kb * 32 + q * 8];
#pragma unroll
        for (int nb = 0; nb < 8; nb++) {
            half8_t bv = *(const half8_t*)(W1p + (size_t)((kb * 8 + nb) * 64 + lane) * 8);
            acc[nb] = __builtin_amdgcn_mfma_f32_16x16x32_f16(av, bv, acc[nb], 0, 0, 0);
        }
    }
#pragma unroll
    for (int nb = 0; nb < 8; nb++) {
        int col = nb * 16 + r16;
        float bb = b1[col];
#pragma unroll
        for (int r = 0; r < 4; r++) {
            float v = acc[nb][r] + bb;
            sG[(w * 16 + q * 4 + r) * 136 + col] = (_Float16)gelu_fast(v);
        }
    }
    // wave w writes exactly the sG rows it reads below — no barrier needed

#pragma unroll
    for (int nb = 0; nb < 8; nb++) acc[nb] = floatx4{0.f, 0.f, 0.f, 0.f};
#pragma unroll
    for (int kb = 0; kb < 4; kb++) {
        half8_t av = *(const half8_t*)&sG[mrow * 136 + kb * 32 + q * 8];
#pragma unroll
        for (int nb = 0; nb < 8; nb++) {
            half8_t bv = *(const half8_t*)(W2p + (size_t)((kb * 8 + nb) * 64 + lane) * 8);
            acc[nb] = __builtin_amdgcn_mfma_f32_16x16x32_f16(av, bv, acc[nb], 0, 0, 0);
        }
    }
#pragma unroll
    for (int nb = 0; nb < 8; nb++) {
        int col = nb * 16 + r16;
        float bb = b2[col];
#pragma unroll
        for (int r = 0; r < 4; r++) {
            int n = n0 + w * 16 + q * 4 + r;
            if (n < N_NODES) {
                float v = acc[nb][r] + bb;
                if (LAST) outf[(size_t)n * D + col] = v;
                else      outh[(size_t)n * D + col] = (_Float16)v;
            }
        }
    }
}

// ---------------- launch ----------------

static inline size_t align_up(size_t v, size_t a) { return (v + a - 1) & ~(a - 1); }

extern "C" void kernel_launch(void* const* d_in, const int* in_sizes, int n_in,
                              void* d_out, int out_size, void* d_ws, size_t ws_size,
                              hipStream_t stream) {
    const float* x         = (const float*)d_in[0];
    const float* edge_attr = (const float*)d_in[1];
    const float* W1        = (const float*)d_in[2];
    const float* b1        = (const float*)d_in[3];
    const float* W2        = (const float*)d_in[4];
    const float* b2        = (const float*)d_in[5];
    const float* We        = (const float*)d_in[6];
    const float* be        = (const float*)d_in[7];
    const float* eps       = (const float*)d_in[8];
    const int*   src       = (const int*)d_in[9];
    const int*   dst       = ((const int*)d_in[9]) + N_EDGES;

    char* w = (char*)d_ws;
    int*  off    = (int*)w;  w += align_up((N_NODES + 1) * sizeof(int), 16);
    int*  deg    = (int*)w;  w += align_up(N_NODES * sizeof(int), 16);
    int*  head   = (int*)w;  w += align_up(N_NODES * sizeof(int), 16);
    int*  bsum   = (int*)w;  w += 256;
    int*  srcs   = (int*)w;  w += align_up((size_t)N_EDGES * sizeof(int), 16);
    _Float16* ea_s = (_Float16*)w; w += (size_t)N_EDGES * E_DIM * 2;
    _Float16* xb0  = (_Float16*)w; w += (size_t)N_NODES * D * 2;
    _Float16* xb1  = (_Float16*)w; w += (size_t)N_NODES * D * 2;
    _Float16* h0b  = (_Float16*)w; w += (size_t)N_NODES * D * 2;
    _Float16* Wp   = (_Float16*)w; w += (size_t)6 * 16384 * 2;

    // ---- CSR build (+ ea move into sorted order) ----
    hipMemsetAsync(deg, 0, N_NODES * sizeof(int), stream);
    k_hist<<<(N_EDGES + 255) / 256, 256, 0, stream>>>(dst, deg);
    int nb1 = (N_NODES + 1023) / 1024;
    k_scan1<<<nb1, 256, 0, stream>>>(deg, off + 1, bsum);
    k_scanadd<<<(N_NODES + 255) / 256, 256, 0, stream>>>(off, bsum, head);
    k_scatter<<<(N_EDGES + 255) / 256, 256, 0, stream>>>(src, dst, edge_attr,
                                                         head, srcs, ea_s);

    // ---- prep: x convert + weight packing ----
    k_prep<<<NB_X + NB_W, 256, 0, stream>>>(x, W1, W2, xb0, Wp);

    // ---- 3 layers ----
    _Float16* xcur = xb0;
    _Float16* xnxt = xb1;
    for (int l = 0; l < DEPTH; l++) {
        k_agg<<<N_NODES / 4, 256, 0, stream>>>(
            xcur, ea_s, srcs, off,
            We + (size_t)l * E_DIM * D, be + (size_t)l * D, eps + l, h0b);
        const _Float16* W1p = Wp + (size_t)(l * 2 + 0) * 16384;
        const _Float16* W2p = Wp + (size_t)(l * 2 + 1) * 16384;
        if (l == DEPTH - 1) {
            k_mlp<true><<<(N_NODES + 63) / 64, 256, 0, stream>>>(
                h0b, W1p, b1 + (size_t)l * D, W2p, b2 + (size_t)l * D,
                (float*)d_out, nullptr);
        } else {
            k_mlp<false><<<(N_NODES + 63) / 64, 256, 0, stream>>>(
                h0b, W1p, b1 + (size_t)l * D, W2p, b2 + (size_t)l * D,
                nullptr, xnxt);
        }
        _Float16* tmp = xcur; xcur = xnxt; xnxt = tmp;
    }
}